// Round 5
// baseline (529.599 us; speedup 1.0000x reference)
//
#include <hip/hip_runtime.h>

#define B_    2
#define S_    2048
#define H_    32
#define KVH_  8
#define D_    128
#define QB    64
#define KB    64
#define NT_   (S_ / KB)
#define NREP  (H_ / KVH_)
#define SCALE 0.08838834764831845f  // 128^-0.5

typedef short  short8 __attribute__((ext_vector_type(8)));
typedef float  f32x4  __attribute__((ext_vector_type(4)));

__device__ inline unsigned short f2bf(float f) {
    unsigned int u = __float_as_uint(f);
    u += 0x7fffu + ((u >> 16) & 1u);
    return (unsigned short)(u >> 16);
}

// ---- prepass: build MFMA-fragment-ordered bf16 K and V ----
// Fragment group = 64 lanes x 16 B contiguous (1 KB) -> main-kernel fragment loads
// are perfectly coalesced global_load_dwordx4 at base + lane*16.
// kfb[(bkvh*NT+kt)*16 + (c*4+nt)][lane]  : K[key=kt*64+nt*16+m16][d=c*32+quad*8+j]
// vfb[(bkvh*NT+kt)*16 + (c2*8+dn)][lane] : V[key=kt*64+c2*32+quad*8+j][d=dn*16+m16]
__global__ void prep_kernel(const float* __restrict__ k, const float* __restrict__ v,
                            unsigned short* __restrict__ kfb,
                            unsigned short* __restrict__ vfb) {
    __shared__ unsigned short Kt[64][136];
    __shared__ unsigned short Vt[64][136];
    const int t = threadIdx.x;
    const int kt = blockIdx.x, bkvh = blockIdx.y;
    const int b = bkvh >> 3, kvh = bkvh & 7;
    const size_t rs = KVH_ * D_;
    const float* ks = k + ((size_t)(b * S_ + kt * 64)) * rs + kvh * D_;
    const float* vs = v + ((size_t)(b * S_ + kt * 64)) * rs + kvh * D_;
    #pragma unroll
    for (int i = 0; i < 8; ++i) {
        const int row = (t >> 5) + i * 8;
        const int col = (t & 31) * 4;
        const float4 a = *(const float4*)(ks + (size_t)row * rs + col);
        const float4 c = *(const float4*)(vs + (size_t)row * rs + col);
        ushort4 wa, wc;
        wa.x = f2bf(a.x); wa.y = f2bf(a.y); wa.z = f2bf(a.z); wa.w = f2bf(a.w);
        wc.x = f2bf(c.x); wc.y = f2bf(c.y); wc.z = f2bf(c.z); wc.w = f2bf(c.w);
        *(ushort4*)&Kt[row][col] = wa;
        *(ushort4*)&Vt[row][col] = wc;
    }
    __syncthreads();
    const int lane = t & 63, m16 = lane & 15, quad = lane >> 4;
    unsigned short* kout = kfb + (size_t)(bkvh * NT_ + kt) * 16 * 512;
    unsigned short* vout = vfb + (size_t)(bkvh * NT_ + kt) * 16 * 512;
    #pragma unroll
    for (int i = 0; i < 4; ++i) {
        const int g = (t >> 6) * 4 + i;          // 0..15
        // K fragment: contiguous b128 read from Kt
        const int c = g >> 2, nt = g & 3;
        const short8 kk = *(const short8*)&Kt[nt * 16 + m16][c * 32 + quad * 8];
        *(short8*)(kout + g * 512 + lane * 8) = kk;
        // V fragment: column gather from Vt
        const int c2 = g >> 3, dn = g & 7;
        short8 vv;
        #pragma unroll
        for (int j = 0; j < 8; ++j)
            vv[j] = (short)Vt[c2 * 32 + quad * 8 + j][dn * 16 + m16];
        *(short8*)(vout + g * 512 + lane * 8) = vv;
    }
}

// ---- main flash kernel: no __syncthreads in the K-loop, no K/V LDS staging ----
// Shared buffer is a union: K-loop uses it as Psh (bf16 P round-trip, wave-private
// rows); epilogue (after one barrier) reuses it as the fp32 O transpose slab
// (round-3-verified layout).
#define P_STRIDE 72
__global__ __launch_bounds__(256, 4) void fa5_kernel(
    const float* __restrict__ q, const unsigned short* __restrict__ kfb,
    const unsigned short* __restrict__ vfb, float* __restrict__ out) {

    __shared__ __align__(16) char smem[4 * 16 * 128 * 4];   // 32 KB
    unsigned short* Psh = (unsigned short*)smem;             // loop phase: 18,432 B used

    const int t    = threadIdx.x;
    const int wave = t >> 6;
    const int lane = t & 63;
    const int m16  = lane & 15;
    const int quad = lane >> 4;

    const int qt  = (S_ / QB - 1) - blockIdx.x;  // heavy tiles first
    const int bh  = blockIdx.y;
    const int b   = bh >> 5;
    const int h   = bh & 31;
    const int kvh = h >> 2;
    const int qbase = qt * QB;

    // ---- Q A-fragments direct from global fp32 (once) ----
    short8 qf[4];
    {
        const float* qp = q + (size_t)(b * S_ + qbase + wave * 16 + m16) * (H_ * D_) + h * D_;
        #pragma unroll
        for (int c = 0; c < 4; ++c) {
            const float4 x0 = *(const float4*)(qp + c * 32 + quad * 8);
            const float4 x1 = *(const float4*)(qp + c * 32 + quad * 8 + 4);
            short8 f;
            f[0] = (short)f2bf(x0.x); f[1] = (short)f2bf(x0.y);
            f[2] = (short)f2bf(x0.z); f[3] = (short)f2bf(x0.w);
            f[4] = (short)f2bf(x1.x); f[5] = (short)f2bf(x1.y);
            f[6] = (short)f2bf(x1.z); f[7] = (short)f2bf(x1.w);
            qf[c] = f;
        }
    }

    // per-lane fragment base pointers (short8 units); one tile = 1024 short8
    const short8* kq = (const short8*)kfb + (size_t)(b * KVH_ + kvh) * NT_ * 1024 + lane;
    const short8* vq = (const short8*)vfb + (size_t)(b * KVH_ + kvh) * NT_ * 1024 + lane;

    f32x4 o[8];
    #pragma unroll
    for (int i = 0; i < 8; ++i) o[i] = (f32x4){0.f, 0.f, 0.f, 0.f};
    float m_i[4], l_i[4];
    #pragma unroll
    for (int r = 0; r < 4; ++r) { m_i[r] = -INFINITY; l_i[r] = 0.f; }

    for (int kt = 0; kt <= qt; ++kt, kq += 1024, vq += 1024) {
        const int kb = kt * KB;

        // ---- S = Q K^T : K B-frags as coalesced dwordx4 from global (L1/L2-hot) ----
        f32x4 sa[4];
        #pragma unroll
        for (int nt = 0; nt < 4; ++nt) sa[nt] = (f32x4){0.f, 0.f, 0.f, 0.f};
        #pragma unroll
        for (int c = 0; c < 4; ++c) {
            short8 kf[4];
            #pragma unroll
            for (int nt = 0; nt < 4; ++nt)
                kf[nt] = kq[(c * 4 + nt) * 64];
            #pragma unroll
            for (int nt = 0; nt < 4; ++nt)
                sa[nt] = __builtin_amdgcn_mfma_f32_16x16x32_bf16(qf[c], kf[nt], sa[nt], 0, 0, 0);
        }

        // ---- scale + causal mask ----
        const bool diag = (kt == qt);
        float p[4][4];
        #pragma unroll
        for (int nt = 0; nt < 4; ++nt) {
            #pragma unroll
            for (int r = 0; r < 4; ++r) {
                float sv = sa[nt][r] * SCALE;
                if (diag) {
                    const int rowg = qbase + wave * 16 + quad * 4 + r;
                    const int colg = kb + nt * 16 + m16;
                    if (colg > rowg) sv = -INFINITY;
                }
                p[nt][r] = sv;
            }
        }

        // ---- online softmax (reduce across the quad-row's 16 lanes) ----
        float alpha[4];
        #pragma unroll
        for (int r = 0; r < 4; ++r) {
            float mv = fmaxf(fmaxf(p[0][r], p[1][r]), fmaxf(p[2][r], p[3][r]));
            mv = fmaxf(mv, __shfl_xor(mv, 1));
            mv = fmaxf(mv, __shfl_xor(mv, 2));
            mv = fmaxf(mv, __shfl_xor(mv, 4));
            mv = fmaxf(mv, __shfl_xor(mv, 8));
            const float mnew = fmaxf(m_i[r], mv);
            alpha[r] = __expf(m_i[r] - mnew);
            m_i[r] = mnew;
            float rs = 0.f;
            #pragma unroll
            for (int nt = 0; nt < 4; ++nt) {
                const float e = __expf(p[nt][r] - mnew);
                p[nt][r] = e;
                rs += e;
            }
            rs += __shfl_xor(rs, 1);
            rs += __shfl_xor(rs, 2);
            rs += __shfl_xor(rs, 4);
            rs += __shfl_xor(rs, 8);
            l_i[r] = l_i[r] * alpha[r] + rs;
        }

        // ---- P: C-layout -> LDS (wave-private rows) ----
        #pragma unroll
        for (int nt = 0; nt < 4; ++nt)
            #pragma unroll
            for (int r = 0; r < 4; ++r)
                Psh[(wave * 16 + quad * 4 + r) * P_STRIDE + nt * 16 + m16] = f2bf(p[nt][r]);

        // rescale O while P writes drain (round-2/3-verified form)
        #pragma unroll
        for (int dn = 0; dn < 8; ++dn)
            #pragma unroll
            for (int r = 0; r < 4; ++r)
                o[dn][r] *= alpha[r];

        asm volatile("s_waitcnt lgkmcnt(0)" ::: "memory");
        const short8 pf0 = *(const short8*)&Psh[(wave * 16 + m16) * P_STRIDE + quad * 8];
        const short8 pf1 = *(const short8*)&Psh[(wave * 16 + m16) * P_STRIDE + 32 + quad * 8];

        // ---- O += P V : V B-frags coalesced from global ----
        #pragma unroll
        for (int c2 = 0; c2 < 2; ++c2) {
            const short8 pf = c2 ? pf1 : pf0;
            #pragma unroll
            for (int dn = 0; dn < 8; ++dn) {
                const short8 vf = vq[(c2 * 8 + dn) * 64];
                o[dn] = __builtin_amdgcn_mfma_f32_16x16x32_bf16(pf, vf, o[dn], 0, 0, 0);
            }
        }
    }

    // ---- epilogue (round-3-verified): normalize, full-slab LDS transpose, float4 stores ----
    float inv[4];
    #pragma unroll
    for (int r = 0; r < 4; ++r) inv[r] = 1.f / l_i[r];

    __syncthreads();  // end of Psh use; reuse smem as fp32 O-slab
    float* Ot = (float*)smem + wave * (16 * 128);   // per-wave [16][128] fp32
    #pragma unroll
    for (int dn = 0; dn < 8; ++dn)
        #pragma unroll
        for (int r = 0; r < 4; ++r)
            Ot[(quad * 4 + r) * 128 + dn * 16 + m16] = o[dn][r] * inv[r];

    asm volatile("s_waitcnt lgkmcnt(0)" ::: "memory");
    float* og = out + (size_t)(b * S_ + qbase + wave * 16) * (H_ * D_) + h * D_;
    #pragma unroll
    for (int i = 0; i < 8; ++i) {
        const int row = (lane >> 5) + i * 2;
        const int col = (lane & 31) * 4;
        *(float4*)(og + (size_t)row * (H_ * D_) + col) = *(const float4*)(Ot + row * 128 + col);
    }
}
#undef P_STRIDE

extern "C" void kernel_launch(void* const* d_in, const int* in_sizes, int n_in,
                              void* d_out, int out_size, void* d_ws, size_t ws_size,
                              hipStream_t stream) {
    const float* q = (const float*)d_in[0];
    const float* k = (const float*)d_in[1];
    const float* v = (const float*)d_in[2];
    float* out = (float*)d_out;

    unsigned short* kfb = (unsigned short*)d_ws;                                  // 8 MB
    unsigned short* vfb = (unsigned short*)d_ws + (size_t)B_ * KVH_ * S_ * D_;    // 8 MB

    prep_kernel<<<dim3(NT_, B_ * KVH_), dim3(256), 0, stream>>>(k, v, kfb, vfb);
    fa5_kernel<<<dim3(S_ / QB, B_ * H_), dim3(256), 0, stream>>>(q, kfb, vfb, out);
}

// Round 6
// 390.742 us; speedup vs baseline: 1.3554x; 1.3554x over previous
//
#include <hip/hip_runtime.h>

#define B_    2
#define S_    2048
#define H_    32
#define KVH_  8
#define D_    128
#define QB    128
#define KB    64
#define NT_   (S_ / KB)
#define NREP  (H_ / KVH_)
#define SCALE 0.08838834764831845f  // 128^-0.5

typedef short  short8 __attribute__((ext_vector_type(8)));
typedef float  f32x4  __attribute__((ext_vector_type(4)));

__device__ inline unsigned short f2bf(float f) {
    unsigned int u = __float_as_uint(f);
    u += 0x7fffu + ((u >> 16) & 1u);
    return (unsigned short)(u >> 16);
}

// ---- prepass: build MFMA-fragment-ordered bf16 K and V (verified round 5) ----
// kfb[(bkvh*NT+kt)*16 + (c*4+nt)][lane]  : K[key=kt*64+nt*16+m16][d=c*32+quad*8+j]
// vfb[(bkvh*NT+kt)*16 + (c2*8+dn)][lane] : V[key=kt*64+c2*32+quad*8+j][d=dn*16+m16]
__global__ void prep_kernel(const float* __restrict__ k, const float* __restrict__ v,
                            unsigned short* __restrict__ kfb,
                            unsigned short* __restrict__ vfb) {
    __shared__ unsigned short Kt[64][136];
    __shared__ unsigned short Vt[64][136];
    const int t = threadIdx.x;
    const int kt = blockIdx.x, bkvh = blockIdx.y;
    const int b = bkvh >> 3, kvh = bkvh & 7;
    const size_t rs = KVH_ * D_;
    const float* ks = k + ((size_t)(b * S_ + kt * 64)) * rs + kvh * D_;
    const float* vs = v + ((size_t)(b * S_ + kt * 64)) * rs + kvh * D_;
    #pragma unroll
    for (int i = 0; i < 8; ++i) {
        const int row = (t >> 5) + i * 8;
        const int col = (t & 31) * 4;
        const float4 a = *(const float4*)(ks + (size_t)row * rs + col);
        const float4 c = *(const float4*)(vs + (size_t)row * rs + col);
        ushort4 wa, wc;
        wa.x = f2bf(a.x); wa.y = f2bf(a.y); wa.z = f2bf(a.z); wa.w = f2bf(a.w);
        wc.x = f2bf(c.x); wc.y = f2bf(c.y); wc.z = f2bf(c.z); wc.w = f2bf(c.w);
        *(ushort4*)&Kt[row][col] = wa;
        *(ushort4*)&Vt[row][col] = wc;
    }
    __syncthreads();
    const int lane = t & 63, m16 = lane & 15, quad = lane >> 4;
    unsigned short* kout = kfb + (size_t)(bkvh * NT_ + kt) * 16 * 512;
    unsigned short* vout = vfb + (size_t)(bkvh * NT_ + kt) * 16 * 512;
    #pragma unroll
    for (int i = 0; i < 4; ++i) {
        const int g = (t >> 6) * 4 + i;          // 0..15
        const int c = g >> 2, nt = g & 3;
        const short8 kk = *(const short8*)&Kt[nt * 16 + m16][c * 32 + quad * 8];
        *(short8*)(kout + g * 512 + lane * 8) = kk;
        const int c2 = g >> 3, dn = g & 7;
        short8 vv;
        #pragma unroll
        for (int j = 0; j < 8; ++j)
            vv[j] = (short)Vt[c2 * 32 + quad * 8 + j][dn * 16 + m16];
        *(short8*)(vout + g * 512 + lane * 8) = vv;
    }
}

// ---- main flash kernel: QB=128 (two 64-row blocks/wave), barrier-free K-loop ----
// LDS union: loop phase Psh[128][72] bf16 (wave-private rows, 18.4 KB);
// epilogue fp32 slab 4 waves x [16][128] (32 KB), one __syncthreads between.
#define P_STRIDE 72
__global__ __launch_bounds__(256, 2) void fa6_kernel(
    const float* __restrict__ q, const unsigned short* __restrict__ kfb,
    const unsigned short* __restrict__ vfb, float* __restrict__ out) {

    __shared__ __align__(16) char smem[4 * 16 * 128 * 4];   // 32 KB
    unsigned short* Psh = (unsigned short*)smem;

    const int t    = threadIdx.x;
    const int wave = t >> 6;
    const int lane = t & 63;
    const int m16  = lane & 15;
    const int quad = lane >> 4;

    const int qtile = (S_ / QB - 1) - blockIdx.x;  // heavy tiles first
    const int bh  = blockIdx.y;
    const int b   = bh >> 5;
    const int h   = bh & 31;
    const int kvh = h >> 2;
    const int qbase = qtile * QB;

    // ---- Q A-fragments for both row-blocks (rows qbase + rb*64 + wave*16 + m16) ----
    short8 qf[2][4];
    #pragma unroll
    for (int rb = 0; rb < 2; ++rb) {
        const float* qp = q + (size_t)(b * S_ + qbase + rb * 64 + wave * 16 + m16) * (H_ * D_) + h * D_;
        #pragma unroll
        for (int c = 0; c < 4; ++c) {
            const float4 x0 = *(const float4*)(qp + c * 32 + quad * 8);
            const float4 x1 = *(const float4*)(qp + c * 32 + quad * 8 + 4);
            short8 f;
            f[0] = (short)f2bf(x0.x); f[1] = (short)f2bf(x0.y);
            f[2] = (short)f2bf(x0.z); f[3] = (short)f2bf(x0.w);
            f[4] = (short)f2bf(x1.x); f[5] = (short)f2bf(x1.y);
            f[6] = (short)f2bf(x1.z); f[7] = (short)f2bf(x1.w);
            qf[rb][c] = f;
        }
    }

    const short8* kq = (const short8*)kfb + (size_t)(b * KVH_ + kvh) * NT_ * 1024 + lane;
    const short8* vq = (const short8*)vfb + (size_t)(b * KVH_ + kvh) * NT_ * 1024 + lane;

    f32x4 o[2][8];
    #pragma unroll
    for (int rb = 0; rb < 2; ++rb)
        #pragma unroll
        for (int i = 0; i < 8; ++i) o[rb][i] = (f32x4){0.f, 0.f, 0.f, 0.f};
    float m_i[2][4], l_i[2][4];
    #pragma unroll
    for (int rb = 0; rb < 2; ++rb)
        #pragma unroll
        for (int r = 0; r < 4; ++r) { m_i[rb][r] = -INFINITY; l_i[rb][r] = 0.f; }

    const int ktmax = 2 * qtile + 1;   // k-tiles 0..ktmax cover keys < qbase+128

    for (int ktt = 0; ktt <= ktmax; ++ktt, kq += 1024, vq += 1024) {
        const int kb = ktt * KB;

        // ---- S = Q K^T for both row-blocks (K frags loaded once, used twice) ----
        f32x4 sa[2][4];
        #pragma unroll
        for (int rb = 0; rb < 2; ++rb)
            #pragma unroll
            for (int nt = 0; nt < 4; ++nt) sa[rb][nt] = (f32x4){0.f, 0.f, 0.f, 0.f};
        #pragma unroll
        for (int c = 0; c < 4; ++c) {
            short8 kf[4];
            #pragma unroll
            for (int nt = 0; nt < 4; ++nt)
                kf[nt] = kq[(c * 4 + nt) * 64];
            #pragma unroll
            for (int nt = 0; nt < 4; ++nt) {
                sa[0][nt] = __builtin_amdgcn_mfma_f32_16x16x32_bf16(qf[0][c], kf[nt], sa[0][nt], 0, 0, 0);
                sa[1][nt] = __builtin_amdgcn_mfma_f32_16x16x32_bf16(qf[1][c], kf[nt], sa[1][nt], 0, 0, 0);
            }
        }

        // ---- issue all V-frag loads now; latency hides under softmax ----
        short8 vf[16];
        #pragma unroll
        for (int g = 0; g < 16; ++g) vf[g] = vq[g * 64];

        // ---- mask + online softmax + P write + O rescale, per row-block ----
        const bool dodiag = (ktt >= 2 * qtile);   // only the last two k-tiles can cross the diagonal
        #pragma unroll
        for (int rb = 0; rb < 2; ++rb) {
            float p[4][4];
            #pragma unroll
            for (int nt = 0; nt < 4; ++nt) {
                #pragma unroll
                for (int r = 0; r < 4; ++r) {
                    float sv = sa[rb][nt][r] * SCALE;
                    if (dodiag) {
                        const int rowg = qbase + rb * 64 + wave * 16 + quad * 4 + r;
                        const int colg = kb + nt * 16 + m16;
                        if (colg > rowg) sv = -INFINITY;
                    }
                    p[nt][r] = sv;
                }
            }
            float alpha[4];
            #pragma unroll
            for (int r = 0; r < 4; ++r) {
                float mv = fmaxf(fmaxf(p[0][r], p[1][r]), fmaxf(p[2][r], p[3][r]));
                mv = fmaxf(mv, __shfl_xor(mv, 1));
                mv = fmaxf(mv, __shfl_xor(mv, 2));
                mv = fmaxf(mv, __shfl_xor(mv, 4));
                mv = fmaxf(mv, __shfl_xor(mv, 8));
                const float mnew = fmaxf(m_i[rb][r], mv);
                alpha[r] = __expf(m_i[rb][r] - mnew);
                m_i[rb][r] = mnew;
                float rs = 0.f;
                #pragma unroll
                for (int nt = 0; nt < 4; ++nt) {
                    const float e = __expf(p[nt][r] - mnew);
                    p[nt][r] = e;
                    rs += e;
                }
                rs += __shfl_xor(rs, 1);
                rs += __shfl_xor(rs, 2);
                rs += __shfl_xor(rs, 4);
                rs += __shfl_xor(rs, 8);
                l_i[rb][r] = l_i[rb][r] * alpha[r] + rs;
            }
            #pragma unroll
            for (int nt = 0; nt < 4; ++nt)
                #pragma unroll
                for (int r = 0; r < 4; ++r)
                    Psh[(rb * 64 + wave * 16 + quad * 4 + r) * P_STRIDE + nt * 16 + m16] = f2bf(p[nt][r]);
            #pragma unroll
            for (int dn = 0; dn < 8; ++dn)
                #pragma unroll
                for (int r = 0; r < 4; ++r)
                    o[rb][dn][r] *= alpha[r];
        }

        // same-wave LDS RAW: drain P writes, read A-fragments for both row-blocks
        asm volatile("s_waitcnt lgkmcnt(0)" ::: "memory");
        short8 pf[2][2];
        #pragma unroll
        for (int rb = 0; rb < 2; ++rb) {
            pf[rb][0] = *(const short8*)&Psh[(rb * 64 + wave * 16 + m16) * P_STRIDE + quad * 8];
            pf[rb][1] = *(const short8*)&Psh[(rb * 64 + wave * 16 + m16) * P_STRIDE + 32 + quad * 8];
        }

        // ---- O += P V (V frags already in regs) ----
        #pragma unroll
        for (int c2 = 0; c2 < 2; ++c2) {
            #pragma unroll
            for (int dn = 0; dn < 8; ++dn) {
                o[0][dn] = __builtin_amdgcn_mfma_f32_16x16x32_bf16(pf[0][c2], vf[c2 * 8 + dn], o[0][dn], 0, 0, 0);
                o[1][dn] = __builtin_amdgcn_mfma_f32_16x16x32_bf16(pf[1][c2], vf[c2 * 8 + dn], o[1][dn], 0, 0, 0);
            }
        }
    }

    // ---- epilogue: per row-block, full-slab LDS transpose + float4 stores ----
    __syncthreads();  // all waves done with Psh loop region (slab overlaps other waves' P rows)
    float* Ot = (float*)smem + wave * (16 * 128);   // per-wave [16][128] fp32
    #pragma unroll
    for (int rb = 0; rb < 2; ++rb) {
        float inv[4];
        #pragma unroll
        for (int r = 0; r < 4; ++r) inv[r] = 1.f / l_i[rb][r];
        #pragma unroll
        for (int dn = 0; dn < 8; ++dn)
            #pragma unroll
            for (int r = 0; r < 4; ++r)
                Ot[(quad * 4 + r) * 128 + dn * 16 + m16] = o[rb][dn][r] * inv[r];
        asm volatile("s_waitcnt lgkmcnt(0)" ::: "memory");
        float* og = out + (size_t)(b * S_ + qbase + rb * 64 + wave * 16) * (H_ * D_) + h * D_;
        #pragma unroll
        for (int i = 0; i < 8; ++i) {
            const int row = (lane >> 5) + i * 2;
            const int col = (lane & 31) * 4;
            *(float4*)(og + (size_t)row * (H_ * D_) + col) = *(const float4*)(Ot + row * 128 + col);
        }
        // LDS per-wave in-order: rb=1 ds_writes queue after rb=0 ds_reads (WAR safe)
    }
}
#undef P_STRIDE

extern "C" void kernel_launch(void* const* d_in, const int* in_sizes, int n_in,
                              void* d_out, int out_size, void* d_ws, size_t ws_size,
                              hipStream_t stream) {
    const float* q = (const float*)d_in[0];
    const float* k = (const float*)d_in[1];
    const float* v = (const float*)d_in[2];
    float* out = (float*)d_out;

    unsigned short* kfb = (unsigned short*)d_ws;                                  // 8 MB
    unsigned short* vfb = (unsigned short*)d_ws + (size_t)B_ * KVH_ * S_ * D_;    // 8 MB

    prep_kernel<<<dim3(NT_, B_ * KVH_), dim3(256), 0, stream>>>(k, v, kfb, vfb);
    fa6_kernel<<<dim3(S_ / QB, B_ * H_), dim3(256), 0, stream>>>(q, kfb, vfb, out);
}